// Round 7
// baseline (171.705 us; speedup 1.0000x reference)
//
#include <hip/hip_runtime.h>
#include <math.h>

#define T_DIM 1024
#define B_DIM 16
#define C_DIM 1024
#define H_DIM 16
#define K_TAPS 7
#define PAD_LEFT 3
#define OUT_DIM 1024
#define M_DIM (T_DIM * B_DIM)   // 16384
#define HK 112
#define HKP 128
#define KD 1024
#define NT32 (KD / 32)          // 32 K-tiles for the BK=32 kernel

typedef __attribute__((ext_vector_type(8))) short bf16x8;
typedef __attribute__((ext_vector_type(4))) float f32x4;

__device__ __forceinline__ ushort f2bf(float f) {
    union { float f; unsigned u; } v; v.f = f;
    unsigned u = v.u;
    u += 0x7fffu + ((u >> 16) & 1u);
    return (ushort)(u >> 16);
}
__device__ __forceinline__ float bf2f(ushort h) {
    union { unsigned u; float f; } v; v.u = ((unsigned)h) << 16;
    return v.f;
}

// ---------------------------------------------------------------------------
__global__ __launch_bounds__(256) void cvt_bf16x8(const float* __restrict__ in,
                                                  ushort* __restrict__ out,
                                                  int n8) {
    int i = blockIdx.x * blockDim.x + threadIdx.x;
    if (i >= n8) return;
    const float4* p = (const float4*)in;
    float4 a = p[2 * i], b = p[2 * i + 1];
    uint4 o;
    o.x = (unsigned)f2bf(a.x) | ((unsigned)f2bf(a.y) << 16);
    o.y = (unsigned)f2bf(a.z) | ((unsigned)f2bf(a.w) << 16);
    o.z = (unsigned)f2bf(b.x) | ((unsigned)f2bf(b.y) << 16);
    o.w = (unsigned)f2bf(b.z) | ((unsigned)f2bf(b.w) << 16);
    ((uint4*)out)[i] = o;
}

// ---------------------------------------------------------------------------
__global__ void transpose_cvt(const float* __restrict__ W,
                              ushort* __restrict__ Wt,
                              int Kd, int N, int Npad) {
    __shared__ float tile[32][33];
    int n0 = blockIdx.x * 32, k0 = blockIdx.y * 32;
    int tx = threadIdx.x, ty = threadIdx.y;
#pragma unroll
    for (int j = 0; j < 4; ++j) {
        int k = k0 + ty * 4 + j;
        int n = n0 + tx;
        tile[ty * 4 + j][tx] = (n < N) ? W[(size_t)k * N + n] : 0.f;
    }
    __syncthreads();
#pragma unroll
    for (int j = 0; j < 4; ++j) {
        int n = n0 + ty * 4 + j;
        if (n < Npad)
            Wt[(size_t)n * Kd + k0 + tx] = f2bf(tile[tx][ty * 4 + j]);
    }
}

// ---------------------------------------------------------------------------
// 256x128 bf16 MFMA GEMM, BK=32, 256 threads (4 waves 2Mx2N, 128x64/wave),
// dbuf LDS (48 KiB -> 2 blocks/CU for inter-block overlap), counted-vmcnt
// pipeline, linear LDS (64B rows -> wave frag reads are dense 1KB,
// conflict-free without swizzle), setprio + bijective XCD swizzle.
// ---------------------------------------------------------------------------
template <bool OUT_BF16>
__global__ __launch_bounds__(256, 2) void gemm_k32(
    const ushort* __restrict__ A, const ushort* __restrict__ Bt,
    const float* __restrict__ bias, void* __restrict__ Cp, int ldc) {
    __shared__ ushort Ab[2][256 * 32];   // 16 KB each
    __shared__ ushort Bb[2][128 * 32];   // 8 KB each

    const int tid  = threadIdx.x;
    const int lane = tid & 63;
    const int wid  = tid >> 6;
    const int wr = wid >> 1;        // 0..1  (M half, 128 rows)
    const int wc = wid & 1;         // 0..1  (N half, 64 cols)
    const int fr = lane & 15;
    const int fq = lane >> 4;

    // bijective XCD swizzle: 512 wgs, 64 consecutive per XCD
    const int orig = blockIdx.x;
    const int nid  = (orig & 7) * 64 + (orig >> 3);
    const int bm = (nid >> 3) * 256;    // 64 M-tiles
    const int bn = (nid & 7) * 128;     // 8  N-tiles

    // staging: chunk c = i*256 + tid -> row = c>>2, slot16B = c&3 (linear LDS)
    const int rA   = tid >> 2;                       // 0..63
    const int slA  = (tid & 3) * 8;                  // ushort col
    const size_t srcA0 = (size_t)(bm + rA) * KD + slA;
    const size_t srcB0 = (size_t)(bn + rA) * KD + slA;

    // fragment bases (ushort offsets); frag m at +m*512, n at +n*512
    const int aBase0 = (wr * 128 + fr) * 32 + fq * 8;
    const int bBase0 = (wc * 64 + fr) * 32 + fq * 8;

    f32x4 acc[8][4];
#pragma unroll
    for (int m = 0; m < 8; ++m)
#pragma unroll
        for (int n = 0; n < 4; ++n) acc[m][n] = (f32x4){0.f, 0.f, 0.f, 0.f};

    auto stage = [&](int buf, int t) {
        const ushort* Ap = A + srcA0 + t * 32;
        const ushort* Bp = Bt + srcB0 + t * 32;
#pragma unroll
        for (int i = 0; i < 4; ++i)
            __builtin_amdgcn_global_load_lds(
                (const __attribute__((address_space(1))) void*)(Ap + (size_t)i * 64 * KD),
                (__attribute__((address_space(3))) void*)(&Ab[buf][(i * 256 + wid * 64) * 8]),
                16, 0, 0);
#pragma unroll
        for (int i = 0; i < 2; ++i)
            __builtin_amdgcn_global_load_lds(
                (const __attribute__((address_space(1))) void*)(Bp + (size_t)i * 64 * KD),
                (__attribute__((address_space(3))) void*)(&Bb[buf][(i * 256 + wid * 64) * 8]),
                16, 0, 0);
    };

    // prologue: tiles 0 and 1 in flight; wait only for tile 0 (6 loads/tile)
    stage(0, 0);
    stage(1, 1);
    asm volatile("s_waitcnt vmcnt(6)" ::: "memory");
    __builtin_amdgcn_sched_barrier(0);
    __builtin_amdgcn_s_barrier();

#pragma unroll 1
    for (int t = 0; t < NT32; ++t) {
        const int cur = t & 1;
        const ushort* Ac = &Ab[cur][0];
        const ushort* Bc = &Bb[cur][0];

        bf16x8 a[8], b[4];
#pragma unroll
        for (int n = 0; n < 4; ++n)
            b[n] = *(const bf16x8*)(Bc + bBase0 + n * 512);
#pragma unroll
        for (int m = 0; m < 8; ++m)
            a[m] = *(const bf16x8*)(Ac + aBase0 + m * 512);

        // all ds_reads of buf[cur] done -> buffer free after barrier
        asm volatile("s_waitcnt lgkmcnt(0)" ::: "memory");
        __builtin_amdgcn_sched_barrier(0);
        __builtin_amdgcn_s_barrier();

        if (t < NT32 - 2) stage(cur, t + 2);

        __builtin_amdgcn_s_setprio(1);
#pragma unroll
        for (int m = 0; m < 8; ++m)
#pragma unroll
            for (int n = 0; n < 4; ++n)
                acc[m][n] = __builtin_amdgcn_mfma_f32_16x16x32_bf16(
                    a[m], b[n], acc[m][n], 0, 0, 0);
        __builtin_amdgcn_s_setprio(0);

        if (t < NT32 - 2) {
            asm volatile("s_waitcnt vmcnt(6)" ::: "memory");  // tile t+1 landed
        } else if (t == NT32 - 2) {
            asm volatile("s_waitcnt vmcnt(0)" ::: "memory");  // last tile landed
        }
        __builtin_amdgcn_sched_barrier(0);
        if (t < NT32 - 1) __builtin_amdgcn_s_barrier();
    }

    // epilogue: C/D layout col=lane&15, row=(lane>>4)*4+r
#pragma unroll
    for (int n = 0; n < 4; ++n) {
        int col = bn + wc * 64 + n * 16 + fr;
        float bv = bias[col];
#pragma unroll
        for (int m = 0; m < 8; ++m) {
#pragma unroll
            for (int r = 0; r < 4; ++r) {
                int row = bm + wr * 128 + m * 16 + fq * 4 + r;
                float v = acc[m][n][r] + bv;
                if (OUT_BF16)
                    ((ushort*)Cp)[(size_t)row * ldc + col] = f2bf(v);
                else
                    ((float*)Cp)[(size_t)row * ldc + col] = v;
            }
        }
    }
}

// ---------------------------------------------------------------------------
// m97-style 128x128 GEMM for the small N=112 GEMM2
// ---------------------------------------------------------------------------
template <bool OUT_BF16, bool NGUARD>
__global__ __launch_bounds__(256) void gemm_mfma(const ushort* __restrict__ A,
                                                 const ushort* __restrict__ Bt,
                                                 const float* __restrict__ bias,
                                                 void* __restrict__ Cp,
                                                 int Kd, int N, int ldc) {
    __shared__ ushort Als[128 * 32];
    __shared__ ushort Bls[128 * 32];
    const int tid  = threadIdx.x;
    const int lane = tid & 63;
    const int wid  = tid >> 6;
    const int wr = wid >> 1, wc = wid & 1;
    const int bm = blockIdx.y * 128, bn = blockIdx.x * 128;
    const int fq = lane >> 4, fr = lane & 15;

    f32x4 acc[4][4];
#pragma unroll
    for (int m = 0; m < 4; ++m)
#pragma unroll
        for (int n = 0; n < 4; ++n) acc[m][n] = (f32x4){0.f, 0.f, 0.f, 0.f};

    const int c0 = wid * 128 + lane;
    const int c1 = c0 + 64;
    const int r0 = c0 >> 2, o0 = (c0 & 3) * 8;
    const int r1 = c1 >> 2, o1 = (c1 & 3) * 8;

    for (int k0 = 0; k0 < Kd; k0 += 32) {
        __builtin_amdgcn_global_load_lds(
            (const __attribute__((address_space(1))) void*)&A[(size_t)(bm + r0) * Kd + k0 + o0],
            (__attribute__((address_space(3))) void*)&Als[(wid * 2 + 0) * 512], 16, 0, 0);
        __builtin_amdgcn_global_load_lds(
            (const __attribute__((address_space(1))) void*)&A[(size_t)(bm + r1) * Kd + k0 + o1],
            (__attribute__((address_space(3))) void*)&Als[(wid * 2 + 1) * 512], 16, 0, 0);
        __builtin_amdgcn_global_load_lds(
            (const __attribute__((address_space(1))) void*)&Bt[(size_t)(bn + r0) * Kd + k0 + o0],
            (__attribute__((address_space(3))) void*)&Bls[(wid * 2 + 0) * 512], 16, 0, 0);
        __builtin_amdgcn_global_load_lds(
            (const __attribute__((address_space(1))) void*)&Bt[(size_t)(bn + r1) * Kd + k0 + o1],
            (__attribute__((address_space(3))) void*)&Bls[(wid * 2 + 1) * 512], 16, 0, 0);
        __syncthreads();

        bf16x8 af[4], bfr[4];
#pragma unroll
        for (int m = 0; m < 4; ++m)
            af[m] = *(const bf16x8*)&Als[(wr * 64 + m * 16 + fr) * 32 + fq * 8];
#pragma unroll
        for (int n = 0; n < 4; ++n)
            bfr[n] = *(const bf16x8*)&Bls[(wc * 64 + n * 16 + fr) * 32 + fq * 8];
#pragma unroll
        for (int m = 0; m < 4; ++m)
#pragma unroll
            for (int n = 0; n < 4; ++n)
                acc[m][n] = __builtin_amdgcn_mfma_f32_16x16x32_bf16(
                    af[m], bfr[n], acc[m][n], 0, 0, 0);
        __syncthreads();
    }

#pragma unroll
    for (int m = 0; m < 4; ++m) {
#pragma unroll
        for (int n = 0; n < 4; ++n) {
            int col = bn + wc * 64 + n * 16 + fr;
            if (NGUARD && col >= N) continue;
            float bv = bias[col];
#pragma unroll
            for (int r = 0; r < 4; ++r) {
                int row = bm + wr * 64 + m * 16 + fq * 4 + r;
                float v = acc[m][n][r] + bv;
                if (OUT_BF16)
                    ((ushort*)Cp)[(size_t)row * ldc + col] = f2bf(v);
                else
                    ((float*)Cp)[(size_t)row * ldc + col] = v;
            }
        }
    }
}

// ---------------------------------------------------------------------------
// Dynamic conv with fused per-head softmax over the 7 taps.
// ---------------------------------------------------------------------------
__global__ __launch_bounds__(256) void dynconv_bf16(const ushort* __restrict__ h,
                                                    const float* __restrict__ q,
                                                    const float* __restrict__ cbias,
                                                    ushort* __restrict__ out) {
    const int m = blockIdx.x;
    const int t = m >> 4;
    const int b = m & 15;

    __shared__ float wsm[HK];
    if (threadIdx.x < HK)
        wsm[threadIdx.x] = q[(size_t)m * HK + threadIdx.x];
    __syncthreads();
    if (threadIdx.x < H_DIM) {
        float* p = &wsm[threadIdx.x * K_TAPS];
        float mx = p[0];
#pragma unroll
        for (int k = 1; k < K_TAPS; ++k) mx = fmaxf(mx, p[k]);
        float e[K_TAPS], s = 0.f;
#pragma unroll
        for (int k = 0; k < K_TAPS; ++k) { e[k] = __expf(p[k] - mx); s += e[k]; }
        float inv = 1.f / s;
#pragma unroll
        for (int k = 0; k < K_TAPS; ++k) p[k] = e[k] * inv;
    }
    __syncthreads();

    const int c = threadIdx.x * 4;
    const int hh = c >> 6;

    float4 bias = *(const float4*)&cbias[c];
    float a0 = bias.x, a1 = bias.y, a2 = bias.z, a3 = bias.w;

#pragma unroll
    for (int k = 0; k < K_TAPS; ++k) {
        int tt = t + k - PAD_LEFT;
        if (tt < 0 || tt >= T_DIM) continue;
        ushort4 hv = *(const ushort4*)&h[((size_t)tt * B_DIM + b) * C_DIM + c];
        float wk = wsm[hh * K_TAPS + k];
        a0 = fmaf(bf2f(hv.x), wk, a0);
        a1 = fmaf(bf2f(hv.y), wk, a1);
        a2 = fmaf(bf2f(hv.z), wk, a2);
        a3 = fmaf(bf2f(hv.w), wk, a3);
    }
    ushort4 o;
    o.x = f2bf(a0); o.y = f2bf(a1); o.z = f2bf(a2); o.w = f2bf(a3);
    *(ushort4*)&out[(size_t)m * C_DIM + c] = o;
}

// ---------------------------------------------------------------------------
extern "C" void kernel_launch(void* const* d_in, const int* in_sizes, int n_in,
                              void* d_out, int out_size, void* d_ws,
                              size_t ws_size, hipStream_t stream) {
    const float* x     = (const float*)d_in[0];
    const float* W1    = (const float*)d_in[1];
    const float* b1    = (const float*)d_in[2];
    const float* Wq    = (const float*)d_in[3];
    const float* bq    = (const float*)d_in[4];
    const float* cbias = (const float*)d_in[5];
    const float* W2    = (const float*)d_in[6];
    const float* b2    = (const float*)d_in[7];
    float* out = (float*)d_out;

    ushort* xb    = (ushort*)d_ws;
    ushort* hb    = xb    + (size_t)M_DIM * C_DIM;
    ushort* convb = hb    + (size_t)M_DIM * C_DIM;
    ushort* W1t   = convb + (size_t)M_DIM * C_DIM;
    ushort* W2t   = W1t   + (size_t)C_DIM * C_DIM;
    ushort* Wqt   = W2t   + (size_t)C_DIM * OUT_DIM;
    float*  q     = (float*)(Wqt + (size_t)HKP * C_DIM);

    cvt_bf16x8<<<dim3(M_DIM * C_DIM / 8 / 256), dim3(256), 0, stream>>>(
        x, xb, M_DIM * C_DIM / 8);
    transpose_cvt<<<dim3(C_DIM / 32, C_DIM / 32), dim3(32, 8), 0, stream>>>(
        W1, W1t, C_DIM, C_DIM, C_DIM);
    transpose_cvt<<<dim3(HKP / 32, C_DIM / 32), dim3(32, 8), 0, stream>>>(
        Wq, Wqt, C_DIM, HK, HKP);
    transpose_cvt<<<dim3(OUT_DIM / 32, C_DIM / 32), dim3(32, 8), 0, stream>>>(
        W2, W2t, C_DIM, OUT_DIM, OUT_DIM);

    // 1) h = bf16(x @ W1 + b1)   [512 wgs = 2 blocks/CU]
    gemm_k32<true><<<dim3(512), dim3(256), 0, stream>>>(xb, W1t, b1, hb, C_DIM);

    // 2) q = h @ Wq + bq   [16384 x 112]
    gemm_mfma<false, true>
        <<<dim3(1, M_DIM / 128), dim3(256), 0, stream>>>(
            hb, Wqt, bq, q, C_DIM, HK, HK);

    // 3+4) conv = bf16(dynconv(h, softmax(q)) + conv_bias)
    dynconv_bf16<<<dim3(M_DIM), dim3(256), 0, stream>>>(hb, q, cbias, convb);

    // 5) out = conv @ W2 + b2
    gemm_k32<false><<<dim3(512), dim3(256), 0, stream>>>(convb, W2t, b2, out,
                                                         OUT_DIM);
}

// Round 8
// 171.200 us; speedup vs baseline: 1.0030x; 1.0030x over previous
//
#include <hip/hip_runtime.h>
#include <math.h>

#define T_DIM 1024
#define B_DIM 16
#define C_DIM 1024
#define H_DIM 16
#define K_TAPS 7
#define PAD_LEFT 3
#define OUT_DIM 1024
#define M_DIM (T_DIM * B_DIM)   // 16384
#define HK 112
#define HKP 128
#define KD 1024
#define NT32 (KD / 32)          // 32 K-tiles for the BK=32 kernel

typedef __attribute__((ext_vector_type(8))) short bf16x8;
typedef __attribute__((ext_vector_type(4))) float f32x4;

__device__ __forceinline__ ushort f2bf(float f) {
    union { float f; unsigned u; } v; v.f = f;
    unsigned u = v.u;
    u += 0x7fffu + ((u >> 16) & 1u);
    return (ushort)(u >> 16);
}
__device__ __forceinline__ float bf2f(ushort h) {
    union { unsigned u; float f; } v; v.u = ((unsigned)h) << 16;
    return v.f;
}

// ---------------------------------------------------------------------------
__global__ __launch_bounds__(256) void cvt_bf16x8(const float* __restrict__ in,
                                                  ushort* __restrict__ out,
                                                  int n8) {
    int i = blockIdx.x * blockDim.x + threadIdx.x;
    if (i >= n8) return;
    const float4* p = (const float4*)in;
    float4 a = p[2 * i], b = p[2 * i + 1];
    uint4 o;
    o.x = (unsigned)f2bf(a.x) | ((unsigned)f2bf(a.y) << 16);
    o.y = (unsigned)f2bf(a.z) | ((unsigned)f2bf(a.w) << 16);
    o.z = (unsigned)f2bf(b.x) | ((unsigned)f2bf(b.y) << 16);
    o.w = (unsigned)f2bf(b.z) | ((unsigned)f2bf(b.w) << 16);
    ((uint4*)out)[i] = o;
}

// ---------------------------------------------------------------------------
__global__ void transpose_cvt(const float* __restrict__ W,
                              ushort* __restrict__ Wt,
                              int Kd, int N, int Npad) {
    __shared__ float tile[32][33];
    int n0 = blockIdx.x * 32, k0 = blockIdx.y * 32;
    int tx = threadIdx.x, ty = threadIdx.y;
#pragma unroll
    for (int j = 0; j < 4; ++j) {
        int k = k0 + ty * 4 + j;
        int n = n0 + tx;
        tile[ty * 4 + j][tx] = (n < N) ? W[(size_t)k * N + n] : 0.f;
    }
    __syncthreads();
#pragma unroll
    for (int j = 0; j < 4; ++j) {
        int n = n0 + ty * 4 + j;
        if (n < Npad)
            Wt[(size_t)n * Kd + k0 + tx] = f2bf(tile[tx][ty * 4 + j]);
    }
}

// ---------------------------------------------------------------------------
// 256x128 bf16 MFMA GEMM, BK=32, 256 threads (4 waves 2Mx2N, 128x64/wave),
// dbuf LDS (48 KiB -> 2 blocks/CU), counted-vmcnt pipeline.
// LDS swizzle: 16B slot' = slot ^ ((row>>1)&3)  -> conflict-free ds_read_b128
// (verified: each 8-lane cycle-group covers all 32 banks exactly once).
// Applied write-side via pre-swizzled global source col (gload_lds dest linear)
// and read-side via swizzled fragment base; both invariant under +16/+64 rows.
// Inner loop: 12 ds_reads -> MFMA half1 (aH reads in flight under it) ->
// lgkm0+barrier -> stage(t+2) -> MFMA half2 -> vmcnt(6)+barrier.
// ---------------------------------------------------------------------------
template <bool OUT_BF16>
__global__ __launch_bounds__(256, 2) void gemm_k32(
    const ushort* __restrict__ A, const ushort* __restrict__ Bt,
    const float* __restrict__ bias, void* __restrict__ Cp, int ldc) {
    __shared__ ushort Ab[2][256 * 32];   // 16 KB each
    __shared__ ushort Bb[2][128 * 32];   // 8 KB each

    const int tid  = threadIdx.x;
    const int lane = tid & 63;
    const int wid  = tid >> 6;
    const int wr = wid >> 1;        // 0..1  (M half, 128 rows)
    const int wc = wid & 1;         // 0..1  (N half, 64 cols)
    const int fr = lane & 15;
    const int fq = lane >> 4;

    // bijective XCD swizzle: 512 wgs, 64 consecutive per XCD
    const int orig = blockIdx.x;
    const int nid  = (orig & 7) * 64 + (orig >> 3);
    const int bm = (nid >> 3) * 256;    // 64 M-tiles
    const int bn = (nid & 7) * 128;     // 8  N-tiles

    // staging: chunk c = i*256 + tid -> row = c>>2 (= i*64 + tid>>2).
    // LDS dest linear; global col16 pre-swizzled: slot ^ ((row>>1)&3).
    // (row>>1)&3 == (tid>>3)&3, invariant across i (i*64 rows -> +32 after >>1).
    const int rA    = tid >> 2;                              // 0..63
    const int colSw = ((tid & 3) ^ ((tid >> 3) & 3)) * 8;    // ushort col
    const size_t srcA0 = (size_t)(bm + rA) * KD + colSw;
    const size_t srcB0 = (size_t)(bn + rA) * KD + colSw;

    // fragment read bases (ushort offsets); swizzle (fr>>1)&3 invariant under
    // +m*16 / +n*16 / +wr*128 / +wc*64 row offsets -> const +512 strides.
    const int slotSw = (fq ^ ((fr >> 1) & 3)) * 8;
    const int aBase0 = (wr * 128 + fr) * 32 + slotSw;
    const int bBase0 = (wc * 64 + fr) * 32 + slotSw;

    f32x4 acc[8][4];
#pragma unroll
    for (int m = 0; m < 8; ++m)
#pragma unroll
        for (int n = 0; n < 4; ++n) acc[m][n] = (f32x4){0.f, 0.f, 0.f, 0.f};

    auto stage = [&](int buf, int t) {
        const ushort* Ap = A + srcA0 + t * 32;
        const ushort* Bp = Bt + srcB0 + t * 32;
#pragma unroll
        for (int i = 0; i < 4; ++i)
            __builtin_amdgcn_global_load_lds(
                (const __attribute__((address_space(1))) void*)(Ap + (size_t)i * 64 * KD),
                (__attribute__((address_space(3))) void*)(&Ab[buf][(i * 256 + wid * 64) * 8]),
                16, 0, 0);
#pragma unroll
        for (int i = 0; i < 2; ++i)
            __builtin_amdgcn_global_load_lds(
                (const __attribute__((address_space(1))) void*)(Bp + (size_t)i * 64 * KD),
                (__attribute__((address_space(3))) void*)(&Bb[buf][(i * 256 + wid * 64) * 8]),
                16, 0, 0);
    };

    // prologue: tiles 0 and 1 in flight; wait only for tile 0 (6 loads/tile)
    stage(0, 0);
    stage(1, 1);
    asm volatile("s_waitcnt vmcnt(6)" ::: "memory");
    __builtin_amdgcn_sched_barrier(0);
    __builtin_amdgcn_s_barrier();

#pragma unroll 1
    for (int t = 0; t < NT32; ++t) {
        const int cur = t & 1;
        const ushort* Ac = &Ab[cur][0];
        const ushort* Bc = &Bb[cur][0];

        bf16x8 b[4], aL[4], aH[4];
#pragma unroll
        for (int n = 0; n < 4; ++n)
            b[n] = *(const bf16x8*)(Bc + bBase0 + n * 512);
#pragma unroll
        for (int m = 0; m < 4; ++m)
            aL[m] = *(const bf16x8*)(Ac + aBase0 + m * 512);
#pragma unroll
        for (int m = 0; m < 4; ++m)
            aH[m] = *(const bf16x8*)(Ac + aBase0 + (m + 4) * 512);

        // MFMA half 1: needs b+aL (compiler waits lgkmcnt(4)); aH in flight.
        __builtin_amdgcn_s_setprio(1);
#pragma unroll
        for (int m = 0; m < 4; ++m)
#pragma unroll
            for (int n = 0; n < 4; ++n)
                acc[m][n] = __builtin_amdgcn_mfma_f32_16x16x32_bf16(
                    aL[m], b[n], acc[m][n], 0, 0, 0);
        __builtin_amdgcn_s_setprio(0);

        // all ds_reads of buf[cur] done in all waves -> safe to overwrite
        asm volatile("s_waitcnt lgkmcnt(0)" ::: "memory");
        __builtin_amdgcn_sched_barrier(0);
        __builtin_amdgcn_s_barrier();

        if (t < NT32 - 2) stage(cur, t + 2);

        // MFMA half 2 overlaps the gload issue
        __builtin_amdgcn_s_setprio(1);
#pragma unroll
        for (int m = 0; m < 4; ++m)
#pragma unroll
            for (int n = 0; n < 4; ++n)
                acc[m + 4][n] = __builtin_amdgcn_mfma_f32_16x16x32_bf16(
                    aH[m], b[n], acc[m + 4][n], 0, 0, 0);
        __builtin_amdgcn_s_setprio(0);

        if (t < NT32 - 2) {
            asm volatile("s_waitcnt vmcnt(6)" ::: "memory");  // tile t+1 landed
        } else if (t == NT32 - 2) {
            asm volatile("s_waitcnt vmcnt(0)" ::: "memory");  // last tile landed
        }
        __builtin_amdgcn_sched_barrier(0);
        if (t < NT32 - 1) __builtin_amdgcn_s_barrier();
    }

    // epilogue: C/D layout col=lane&15, row=(lane>>4)*4+r
#pragma unroll
    for (int n = 0; n < 4; ++n) {
        int col = bn + wc * 64 + n * 16 + fr;
        float bv = bias[col];
#pragma unroll
        for (int m = 0; m < 8; ++m) {
#pragma unroll
            for (int r = 0; r < 4; ++r) {
                int row = bm + wr * 128 + m * 16 + fq * 4 + r;
                float v = acc[m][n][r] + bv;
                if (OUT_BF16)
                    ((ushort*)Cp)[(size_t)row * ldc + col] = f2bf(v);
                else
                    ((float*)Cp)[(size_t)row * ldc + col] = v;
            }
        }
    }
}

// ---------------------------------------------------------------------------
// m97-style 128x128 GEMM for the small N=112 GEMM2
// ---------------------------------------------------------------------------
template <bool OUT_BF16, bool NGUARD>
__global__ __launch_bounds__(256) void gemm_mfma(const ushort* __restrict__ A,
                                                 const ushort* __restrict__ Bt,
                                                 const float* __restrict__ bias,
                                                 void* __restrict__ Cp,
                                                 int Kd, int N, int ldc) {
    __shared__ ushort Als[128 * 32];
    __shared__ ushort Bls[128 * 32];
    const int tid  = threadIdx.x;
    const int lane = tid & 63;
    const int wid  = tid >> 6;
    const int wr = wid >> 1, wc = wid & 1;
    const int bm = blockIdx.y * 128, bn = blockIdx.x * 128;
    const int fq = lane >> 4, fr = lane & 15;

    f32x4 acc[4][4];
#pragma unroll
    for (int m = 0; m < 4; ++m)
#pragma unroll
        for (int n = 0; n < 4; ++n) acc[m][n] = (f32x4){0.f, 0.f, 0.f, 0.f};

    const int c0 = wid * 128 + lane;
    const int c1 = c0 + 64;
    const int r0 = c0 >> 2, o0 = (c0 & 3) * 8;
    const int r1 = c1 >> 2, o1 = (c1 & 3) * 8;

    for (int k0 = 0; k0 < Kd; k0 += 32) {
        __builtin_amdgcn_global_load_lds(
            (const __attribute__((address_space(1))) void*)&A[(size_t)(bm + r0) * Kd + k0 + o0],
            (__attribute__((address_space(3))) void*)&Als[(wid * 2 + 0) * 512], 16, 0, 0);
        __builtin_amdgcn_global_load_lds(
            (const __attribute__((address_space(1))) void*)&A[(size_t)(bm + r1) * Kd + k0 + o1],
            (__attribute__((address_space(3))) void*)&Als[(wid * 2 + 1) * 512], 16, 0, 0);
        __builtin_amdgcn_global_load_lds(
            (const __attribute__((address_space(1))) void*)&Bt[(size_t)(bn + r0) * Kd + k0 + o0],
            (__attribute__((address_space(3))) void*)&Bls[(wid * 2 + 0) * 512], 16, 0, 0);
        __builtin_amdgcn_global_load_lds(
            (const __attribute__((address_space(1))) void*)&Bt[(size_t)(bn + r1) * Kd + k0 + o1],
            (__attribute__((address_space(3))) void*)&Bls[(wid * 2 + 1) * 512], 16, 0, 0);
        __syncthreads();

        bf16x8 af[4], bfr[4];
#pragma unroll
        for (int m = 0; m < 4; ++m)
            af[m] = *(const bf16x8*)&Als[(wr * 64 + m * 16 + fr) * 32 + fq * 8];
#pragma unroll
        for (int n = 0; n < 4; ++n)
            bfr[n] = *(const bf16x8*)&Bls[(wc * 64 + n * 16 + fr) * 32 + fq * 8];
#pragma unroll
        for (int m = 0; m < 4; ++m)
#pragma unroll
            for (int n = 0; n < 4; ++n)
                acc[m][n] = __builtin_amdgcn_mfma_f32_16x16x32_bf16(
                    af[m], bfr[n], acc[m][n], 0, 0, 0);
        __syncthreads();
    }

#pragma unroll
    for (int m = 0; m < 4; ++m) {
#pragma unroll
        for (int n = 0; n < 4; ++n) {
            int col = bn + wc * 64 + n * 16 + fr;
            if (NGUARD && col >= N) continue;
            float bv = bias[col];
#pragma unroll
            for (int r = 0; r < 4; ++r) {
                int row = bm + wr * 64 + m * 16 + fq * 4 + r;
                float v = acc[m][n][r] + bv;
                if (OUT_BF16)
                    ((ushort*)Cp)[(size_t)row * ldc + col] = f2bf(v);
                else
                    ((float*)Cp)[(size_t)row * ldc + col] = v;
            }
        }
    }
}

// ---------------------------------------------------------------------------
// Dynamic conv with fused per-head softmax over the 7 taps.
// ---------------------------------------------------------------------------
__global__ __launch_bounds__(256) void dynconv_bf16(const ushort* __restrict__ h,
                                                    const float* __restrict__ q,
                                                    const float* __restrict__ cbias,
                                                    ushort* __restrict__ out) {
    const int m = blockIdx.x;
    const int t = m >> 4;
    const int b = m & 15;

    __shared__ float wsm[HK];
    if (threadIdx.x < HK)
        wsm[threadIdx.x] = q[(size_t)m * HK + threadIdx.x];
    __syncthreads();
    if (threadIdx.x < H_DIM) {
        float* p = &wsm[threadIdx.x * K_TAPS];
        float mx = p[0];
#pragma unroll
        for (int k = 1; k < K_TAPS; ++k) mx = fmaxf(mx, p[k]);
        float e[K_TAPS], s = 0.f;
#pragma unroll
        for (int k = 0; k < K_TAPS; ++k) { e[k] = __expf(p[k] - mx); s += e[k]; }
        float inv = 1.f / s;
#pragma unroll
        for (int k = 0; k < K_TAPS; ++k) p[k] = e[k] * inv;
    }
    __syncthreads();

    const int c = threadIdx.x * 4;
    const int hh = c >> 6;

    float4 bias = *(const float4*)&cbias[c];
    float a0 = bias.x, a1 = bias.y, a2 = bias.z, a3 = bias.w;

#pragma unroll
    for (int k = 0; k < K_TAPS; ++k) {
        int tt = t + k - PAD_LEFT;
        if (tt < 0 || tt >= T_DIM) continue;
        ushort4 hv = *(const ushort4*)&h[((size_t)tt * B_DIM + b) * C_DIM + c];
        float wk = wsm[hh * K_TAPS + k];
        a0 = fmaf(bf2f(hv.x), wk, a0);
        a1 = fmaf(bf2f(hv.y), wk, a1);
        a2 = fmaf(bf2f(hv.z), wk, a2);
        a3 = fmaf(bf2f(hv.w), wk, a3);
    }
    ushort4 o;
    o.x = f2bf(a0); o.y = f2bf(a1); o.z = f2bf(a2); o.w = f2bf(a3);
    *(ushort4*)&out[(size_t)m * C_DIM + c] = o;
}

// ---------------------------------------------------------------------------
extern "C" void kernel_launch(void* const* d_in, const int* in_sizes, int n_in,
                              void* d_out, int out_size, void* d_ws,
                              size_t ws_size, hipStream_t stream) {
    const float* x     = (const float*)d_in[0];
    const float* W1    = (const float*)d_in[1];
    const float* b1    = (const float*)d_in[2];
    const float* Wq    = (const float*)d_in[3];
    const float* bq    = (const float*)d_in[4];
    const float* cbias = (const float*)d_in[5];
    const float* W2    = (const float*)d_in[6];
    const float* b2    = (const float*)d_in[7];
    float* out = (float*)d_out;

    ushort* xb    = (ushort*)d_ws;
    ushort* hb    = xb    + (size_t)M_DIM * C_DIM;
    ushort* convb = hb    + (size_t)M_DIM * C_DIM;
    ushort* W1t   = convb + (size_t)M_DIM * C_DIM;
    ushort* W2t   = W1t   + (size_t)C_DIM * C_DIM;
    ushort* Wqt   = W2t   + (size_t)C_DIM * OUT_DIM;
    float*  q     = (float*)(Wqt + (size_t)HKP * C_DIM);

    cvt_bf16x8<<<dim3(M_DIM * C_DIM / 8 / 256), dim3(256), 0, stream>>>(
        x, xb, M_DIM * C_DIM / 8);
    transpose_cvt<<<dim3(C_DIM / 32, C_DIM / 32), dim3(32, 8), 0, stream>>>(
        W1, W1t, C_DIM, C_DIM, C_DIM);
    transpose_cvt<<<dim3(HKP / 32, C_DIM / 32), dim3(32, 8), 0, stream>>>(
        Wq, Wqt, C_DIM, HK, HKP);
    transpose_cvt<<<dim3(OUT_DIM / 32, C_DIM / 32), dim3(32, 8), 0, stream>>>(
        W2, W2t, C_DIM, OUT_DIM, OUT_DIM);

    // 1) h = bf16(x @ W1 + b1)   [512 wgs = 2 blocks/CU]
    gemm_k32<true><<<dim3(512), dim3(256), 0, stream>>>(xb, W1t, b1, hb, C_DIM);

    // 2) q = h @ Wq + bq   [16384 x 112]
    gemm_mfma<false, true>
        <<<dim3(1, M_DIM / 128), dim3(256), 0, stream>>>(
            hb, Wqt, bq, q, C_DIM, HK, HK);

    // 3+4) conv = bf16(dynconv(h, softmax(q)) + conv_bias)
    dynconv_bf16<<<dim3(M_DIM), dim3(256), 0, stream>>>(hb, q, cbias, convb);

    // 5) out = conv @ W2 + b2
    gemm_k32<false><<<dim3(512), dim3(256), 0, stream>>>(convb, W2t, b2, out,
                                                         OUT_DIM);
}

// Round 9
// 165.982 us; speedup vs baseline: 1.0345x; 1.0314x over previous
//
#include <hip/hip_runtime.h>
#include <math.h>

#define T_DIM 1024
#define B_DIM 16
#define C_DIM 1024
#define H_DIM 16
#define K_TAPS 7
#define PAD_LEFT 3
#define OUT_DIM 1024
#define M_DIM (T_DIM * B_DIM)   // 16384
#define HK 112
#define HKP 128
#define KD 1024

typedef __attribute__((ext_vector_type(8))) short bf16x8;
typedef __attribute__((ext_vector_type(4))) float f32x4;

__device__ __forceinline__ ushort f2bf(float f) {
    union { float f; unsigned u; } v; v.f = f;
    unsigned u = v.u;
    u += 0x7fffu + ((u >> 16) & 1u);
    return (ushort)(u >> 16);
}
__device__ __forceinline__ float bf2f(ushort h) {
    union { unsigned u; float f; } v; v.u = ((unsigned)h) << 16;
    return v.f;
}

// ---------------------------------------------------------------------------
__global__ __launch_bounds__(256) void cvt_bf16x8(const float* __restrict__ in,
                                                  ushort* __restrict__ out,
                                                  int n8) {
    int i = blockIdx.x * blockDim.x + threadIdx.x;
    if (i >= n8) return;
    const float4* p = (const float4*)in;
    float4 a = p[2 * i], b = p[2 * i + 1];
    uint4 o;
    o.x = (unsigned)f2bf(a.x) | ((unsigned)f2bf(a.y) << 16);
    o.y = (unsigned)f2bf(a.z) | ((unsigned)f2bf(a.w) << 16);
    o.z = (unsigned)f2bf(b.x) | ((unsigned)f2bf(b.y) << 16);
    o.w = (unsigned)f2bf(b.z) | ((unsigned)f2bf(b.w) << 16);
    ((uint4*)out)[i] = o;
}

// ---------------------------------------------------------------------------
__global__ void transpose_cvt(const float* __restrict__ W,
                              ushort* __restrict__ Wt,
                              int Kd, int N, int Npad) {
    __shared__ float tile[32][33];
    int n0 = blockIdx.x * 32, k0 = blockIdx.y * 32;
    int tx = threadIdx.x, ty = threadIdx.y;
#pragma unroll
    for (int j = 0; j < 4; ++j) {
        int k = k0 + ty * 4 + j;
        int n = n0 + tx;
        tile[ty * 4 + j][tx] = (n < N) ? W[(size_t)k * N + n] : 0.f;
    }
    __syncthreads();
#pragma unroll
    for (int j = 0; j < 4; ++j) {
        int n = n0 + ty * 4 + j;
        if (n < Npad)
            Wt[(size_t)n * Kd + k0 + tx] = f2bf(tile[tx][ty * 4 + j]);
    }
}

// ---------------------------------------------------------------------------
// 256x256 bf16 MFMA GEMM, 8-phase schedule (T3+T4+T2+T5), BK=64, 512 threads
// (8 waves 2Mx4N, 128x64 out/wave). LDS = 8 half-tile slots (tile-parity x
// K-half per matrix) = 128 KiB. Per phase: {ds_read subtile || stage 1
// half-tile -> vmcnt(6) even phases -> barrier -> lgkm0 -> 16 MFMA -> barrier}.
// Swizzle identical to R8 (verified 0 conflicts): 16B slot' = slot^((row>>1)&3)
// applied pre-swizzled-source + swizzled-read (rule #21).
// vmcnt ledger: steady vmcnt(6) at even phases; tail j=7: p2=vmcnt(4),
// p4=vmcnt(0). Prologue: 16 loads + vmcnt(12).
// ---------------------------------------------------------------------------
#define PHASE(P2KS, MH, READB, STAGE_STMT, VM_STMT)                           \
    {                                                                         \
        if (READB) {                                                          \
            _Pragma("unroll")                                                 \
            for (int n = 0; n < 4; ++n)                                       \
                b[n] = *(const bf16x8*)(Bbase + (P2KS)*8192 + bOff + n*512);  \
        }                                                                     \
        bf16x8 a_[4];                                                         \
        _Pragma("unroll")                                                     \
        for (int m = 0; m < 4; ++m)                                           \
            a_[m] = *(const bf16x8*)(Abase + (P2KS)*8192 + aOff +             \
                                     (MH)*2048 + m*512);                      \
        STAGE_STMT;                                                           \
        VM_STMT;                                                              \
        __builtin_amdgcn_s_barrier();                                         \
        asm volatile("s_waitcnt lgkmcnt(0)" ::: "memory");                    \
        __builtin_amdgcn_sched_barrier(0);                                    \
        __builtin_amdgcn_s_setprio(1);                                        \
        _Pragma("unroll")                                                     \
        for (int m = 0; m < 4; ++m)                                           \
            _Pragma("unroll")                                                 \
            for (int n = 0; n < 4; ++n)                                       \
                acc[(MH)*4 + m][n] = __builtin_amdgcn_mfma_f32_16x16x32_bf16( \
                    a_[m], b[n], acc[(MH)*4 + m][n], 0, 0, 0);                \
        __builtin_amdgcn_s_setprio(0);                                        \
        __builtin_amdgcn_s_barrier();                                         \
        __builtin_amdgcn_sched_barrier(0);                                    \
    }

template <bool OUT_BF16>
__global__ __launch_bounds__(512, 1) void gemm8p(
    const ushort* __restrict__ A, const ushort* __restrict__ Bt,
    const float* __restrict__ bias, void* __restrict__ Cp, int ldc) {
    __shared__ ushort Lds[8 * 8192];   // A slots 0-3, B slots 4-7 (par*2+kh)

    const int tid  = threadIdx.x;
    const int lane = tid & 63;
    const int wid  = tid >> 6;
    const int wr = wid >> 2;        // 0..1  (M half, 128 rows)
    const int wc = wid & 3;         // 0..3  (N quarter, 64 cols)
    const int fr = lane & 15;
    const int fq = lane >> 4;

    // bijective XCD swizzle: 256 wgs, 32 consecutive per XCD
    const int orig = blockIdx.x;
    const int nid  = (orig & 7) * 32 + (orig >> 3);
    const int bm = (nid >> 2) * 256;
    const int bn = (nid & 3) * 256;

    // staging: chunk c = i*512 + tid -> row = i*128 + (tid>>2), slot16 = tid&3.
    // pre-swizzled source col: slot ^ ((row>>1)&3) = (tid&3)^((tid>>3)&3).
    const int srow = tid >> 2;                               // 0..127
    const int scol = ((tid & 3) ^ ((tid >> 3) & 3)) * 8;     // ushort col
    const size_t sA = (size_t)(bm + srow) * KD + scol;
    const size_t sB = (size_t)(bn + srow) * KD + scol;
    const int sdst = wid * 64 * 8;   // wave-uniform dest base (+ i*4096)

    // read-side swizzled fragment bases (ushort offsets)
    const int slotSw = (fq ^ ((fr >> 1) & 3)) * 8;
    const int aOff = (wr * 128 + fr) * 32 + slotSw;  // + slot*8192+mh*2048+m*512
    const int bOff = (wc * 64 + fr) * 32 + slotSw;   // + slot*8192+n*512
    const ushort* Abase = &Lds[0];
    const ushort* Bbase = &Lds[4 * 8192];

    f32x4 acc[8][4];
#pragma unroll
    for (int m = 0; m < 8; ++m)
#pragma unroll
        for (int n = 0; n < 4; ++n) acc[m][n] = (f32x4){0.f, 0.f, 0.f, 0.f};

    auto stageA = [&](int slot, int koff) {
#pragma unroll
        for (int i = 0; i < 2; ++i)
            __builtin_amdgcn_global_load_lds(
                (const __attribute__((address_space(1))) void*)(A + sA + koff + (size_t)i * 128 * KD),
                (__attribute__((address_space(3))) void*)(&Lds[slot * 8192 + i * 4096 + sdst]),
                16, 0, 0);
    };
    auto stageB = [&](int slot, int koff) {
#pragma unroll
        for (int i = 0; i < 2; ++i)
            __builtin_amdgcn_global_load_lds(
                (const __attribute__((address_space(1))) void*)(Bt + sB + koff + (size_t)i * 128 * KD),
                (__attribute__((address_space(3))) void*)(&Lds[(4 + slot) * 8192 + i * 4096 + sdst]),
                16, 0, 0);
    };

    // prologue: tiles 0 (slots 0,1) and 1 (slots 2,3), order A00 B00 A01 B01
    // A10 B10 A11 B11 (16 loads); vmcnt(12) -> A00,B00 landed for phase 0.
    stageA(0, 0);   stageB(0, 0);
    stageA(1, 32);  stageB(1, 32);
    stageA(2, 64);  stageB(2, 64);
    stageA(3, 96);  stageB(3, 96);
    asm volatile("s_waitcnt vmcnt(12)" ::: "memory");
    __builtin_amdgcn_sched_barrier(0);
    __builtin_amdgcn_s_barrier();
    __builtin_amdgcn_sched_barrier(0);

#pragma unroll 1
    for (int j = 0; j < 8; ++j) {
        bf16x8 b[4];
        const int e = 2 * j;

        // p0: tile e, k0, mh0 | stage A-k1(2j+1) -> slot A3 | vmcnt(6)
        PHASE(0, 0, 1,
              { if (j >= 1) stageA(3, (e + 1) * 64 + 32); },
              { asm volatile("s_waitcnt vmcnt(6)" ::: "memory");
                __builtin_amdgcn_sched_barrier(0); })
        // p1: tile e, k0, mh1 | stage B-k1(2j+1) -> slot B3
        PHASE(0, 1, 0,
              { if (j >= 1) stageB(3, (e + 1) * 64 + 32); },
              (void)0; )
        // p2: tile e, k1, mh0 | stage A-k0(2j+2) -> slot A0 | vmcnt(6)/(4 tail)
        PHASE(1, 0, 1,
              { if (j < 7) stageA(0, (e + 2) * 64); },
              { if (j == 7) { asm volatile("s_waitcnt vmcnt(4)" ::: "memory"); }
                else        { asm volatile("s_waitcnt vmcnt(6)" ::: "memory"); }
                __builtin_amdgcn_sched_barrier(0); })
        // p3: tile e, k1, mh1 | stage B-k0(2j+2) -> slot B0
        PHASE(1, 1, 0,
              { if (j < 7) stageB(0, (e + 2) * 64); },
              (void)0; )
        // p4: tile e+1, k0, mh0 | stage A-k1(2j+2) -> slot A1 | vmcnt(6)/(0 tail)
        PHASE(2, 0, 1,
              { if (j < 7) stageA(1, (e + 2) * 64 + 32); },
              { if (j == 7) { asm volatile("s_waitcnt vmcnt(0)" ::: "memory"); }
                else        { asm volatile("s_waitcnt vmcnt(6)" ::: "memory"); }
                __builtin_amdgcn_sched_barrier(0); })
        // p5: tile e+1, k0, mh1 | stage B-k1(2j+2) -> slot B1
        PHASE(2, 1, 0,
              { if (j < 7) stageB(1, (e + 2) * 64 + 32); },
              (void)0; )
        // p6: tile e+1, k1, mh0 | stage A-k0(2j+3) -> slot A2 | vmcnt(6)
        PHASE(3, 0, 1,
              { if (j < 7) stageA(2, (e + 3) * 64); },
              { asm volatile("s_waitcnt vmcnt(6)" ::: "memory");
                __builtin_amdgcn_sched_barrier(0); })
        // p7: tile e+1, k1, mh1 | stage B-k0(2j+3) -> slot B2
        PHASE(3, 1, 0,
              { if (j < 7) stageB(2, (e + 3) * 64); },
              (void)0; )
    }

    // epilogue: C/D layout col=lane&15, row=(lane>>4)*4+r
#pragma unroll
    for (int n = 0; n < 4; ++n) {
        int col = bn + wc * 64 + n * 16 + fr;
        float bv = bias[col];
#pragma unroll
        for (int m = 0; m < 8; ++m) {
#pragma unroll
            for (int r = 0; r < 4; ++r) {
                int row = bm + wr * 128 + m * 16 + fq * 4 + r;
                float v = acc[m][n][r] + bv;
                if (OUT_BF16)
                    ((ushort*)Cp)[(size_t)row * ldc + col] = f2bf(v);
                else
                    ((float*)Cp)[(size_t)row * ldc + col] = v;
            }
        }
    }
}

// ---------------------------------------------------------------------------
// m97-style 128x128 GEMM for the small N=112 GEMM2
// ---------------------------------------------------------------------------
template <bool OUT_BF16, bool NGUARD>
__global__ __launch_bounds__(256) void gemm_mfma(const ushort* __restrict__ A,
                                                 const ushort* __restrict__ Bt,
                                                 const float* __restrict__ bias,
                                                 void* __restrict__ Cp,
                                                 int Kd, int N, int ldc) {
    __shared__ ushort Als[128 * 32];
    __shared__ ushort Bls[128 * 32];
    const int tid  = threadIdx.x;
    const int lane = tid & 63;
    const int wid  = tid >> 6;
    const int wr = wid >> 1, wc = wid & 1;
    const int bm = blockIdx.y * 128, bn = blockIdx.x * 128;
    const int fq = lane >> 4, fr = lane & 15;

    f32x4 acc[4][4];
#pragma unroll
    for (int m = 0; m < 4; ++m)
#pragma unroll
        for (int n = 0; n < 4; ++n) acc[m][n] = (f32x4){0.f, 0.f, 0.f, 0.f};

    const int c0 = wid * 128 + lane;
    const int c1 = c0 + 64;
    const int r0 = c0 >> 2, o0 = (c0 & 3) * 8;
    const int r1 = c1 >> 2, o1 = (c1 & 3) * 8;

    for (int k0 = 0; k0 < Kd; k0 += 32) {
        __builtin_amdgcn_global_load_lds(
            (const __attribute__((address_space(1))) void*)&A[(size_t)(bm + r0) * Kd + k0 + o0],
            (__attribute__((address_space(3))) void*)&Als[(wid * 2 + 0) * 512], 16, 0, 0);
        __builtin_amdgcn_global_load_lds(
            (const __attribute__((address_space(1))) void*)&A[(size_t)(bm + r1) * Kd + k0 + o1],
            (__attribute__((address_space(3))) void*)&Als[(wid * 2 + 1) * 512], 16, 0, 0);
        __builtin_amdgcn_global_load_lds(
            (const __attribute__((address_space(1))) void*)&Bt[(size_t)(bn + r0) * Kd + k0 + o0],
            (__attribute__((address_space(3))) void*)&Bls[(wid * 2 + 0) * 512], 16, 0, 0);
        __builtin_amdgcn_global_load_lds(
            (const __attribute__((address_space(1))) void*)&Bt[(size_t)(bn + r1) * Kd + k0 + o1],
            (__attribute__((address_space(3))) void*)&Bls[(wid * 2 + 1) * 512], 16, 0, 0);
        __syncthreads();

        bf16x8 af[4], bfr[4];
#pragma unroll
        for (int m = 0; m < 4; ++m)
            af[m] = *(const bf16x8*)&Als[(wr * 64 + m * 16 + fr) * 32 + fq * 8];
#pragma unroll
        for (int n = 0; n < 4; ++n)
            bfr[n] = *(const bf16x8*)&Bls[(wc * 64 + n * 16 + fr) * 32 + fq * 8];
#pragma unroll
        for (int m = 0; m < 4; ++m)
#pragma unroll
            for (int n = 0; n < 4; ++n)
                acc[m][n] = __builtin_amdgcn_mfma_f32_16x16x32_bf16(
                    af[m], bfr[n], acc[m][n], 0, 0, 0);
        __syncthreads();
    }

#pragma unroll
    for (int m = 0; m < 4; ++m) {
#pragma unroll
        for (int n = 0; n < 4; ++n) {
            int col = bn + wc * 64 + n * 16 + fr;
            if (NGUARD && col >= N) continue;
            float bv = bias[col];
#pragma unroll
            for (int r = 0; r < 4; ++r) {
                int row = bm + wr * 64 + m * 16 + fq * 4 + r;
                float v = acc[m][n][r] + bv;
                if (OUT_BF16)
                    ((ushort*)Cp)[(size_t)row * ldc + col] = f2bf(v);
                else
                    ((float*)Cp)[(size_t)row * ldc + col] = v;
            }
        }
    }
}

// ---------------------------------------------------------------------------
// Dynamic conv with fused per-head softmax over the 7 taps.
// ---------------------------------------------------------------------------
__global__ __launch_bounds__(256) void dynconv_bf16(const ushort* __restrict__ h,
                                                    const float* __restrict__ q,
                                                    const float* __restrict__ cbias,
                                                    ushort* __restrict__ out) {
    const int m = blockIdx.x;
    const int t = m >> 4;
    const int b = m & 15;

    __shared__ float wsm[HK];
    if (threadIdx.x < HK)
        wsm[threadIdx.x] = q[(size_t)m * HK + threadIdx.x];
    __syncthreads();
    if (threadIdx.x < H_DIM) {
        float* p = &wsm[threadIdx.x * K_TAPS];
        float mx = p[0];
#pragma unroll
        for (int k = 1; k < K_TAPS; ++k) mx = fmaxf(mx, p[k]);
        float e[K_TAPS], s = 0.f;
#pragma unroll
        for (int k = 0; k < K_TAPS; ++k) { e[k] = __expf(p[k] - mx); s += e[k]; }
        float inv = 1.f / s;
#pragma unroll
        for (int k = 0; k < K_TAPS; ++k) p[k] = e[k] * inv;
    }
    __syncthreads();

    const int c = threadIdx.x * 4;
    const int hh = c >> 6;

    float4 bias = *(const float4*)&cbias[c];
    float a0 = bias.x, a1 = bias.y, a2 = bias.z, a3 = bias.w;

#pragma unroll
    for (int k = 0; k < K_TAPS; ++k) {
        int tt = t + k - PAD_LEFT;
        if (tt < 0 || tt >= T_DIM) continue;
        ushort4 hv = *(const ushort4*)&h[((size_t)tt * B_DIM + b) * C_DIM + c];
        float wk = wsm[hh * K_TAPS + k];
        a0 = fmaf(bf2f(hv.x), wk, a0);
        a1 = fmaf(bf2f(hv.y), wk, a1);
        a2 = fmaf(bf2f(hv.z), wk, a2);
        a3 = fmaf(bf2f(hv.w), wk, a3);
    }
    ushort4 o;
    o.x = f2bf(a0); o.y = f2bf(a1); o.z = f2bf(a2); o.w = f2bf(a3);
    *(ushort4*)&out[(size_t)m * C_DIM + c] = o;
}

// ---------------------------------------------------------------------------
extern "C" void kernel_launch(void* const* d_in, const int* in_sizes, int n_in,
                              void* d_out, int out_size, void* d_ws,
                              size_t ws_size, hipStream_t stream) {
    const float* x     = (const float*)d_in[0];
    const float* W1    = (const float*)d_in[1];
    const float* b1    = (const float*)d_in[2];
    const float* Wq    = (const float*)d_in[3];
    const float* bq    = (const float*)d_in[4];
    const float* cbias = (const float*)d_in[5];
    const float* W2    = (const float*)d_in[6];
    const float* b2    = (const float*)d_in[7];
    float* out = (float*)d_out;

    ushort* xb    = (ushort*)d_ws;
    ushort* hb    = xb    + (size_t)M_DIM * C_DIM;
    ushort* convb = hb    + (size_t)M_DIM * C_DIM;
    ushort* W1t   = convb + (size_t)M_DIM * C_DIM;
    ushort* W2t   = W1t   + (size_t)C_DIM * C_DIM;
    ushort* Wqt   = W2t   + (size_t)C_DIM * OUT_DIM;
    float*  q     = (float*)(Wqt + (size_t)HKP * C_DIM);

    cvt_bf16x8<<<dim3(M_DIM * C_DIM / 8 / 256), dim3(256), 0, stream>>>(
        x, xb, M_DIM * C_DIM / 8);
    transpose_cvt<<<dim3(C_DIM / 32, C_DIM / 32), dim3(32, 8), 0, stream>>>(
        W1, W1t, C_DIM, C_DIM, C_DIM);
    transpose_cvt<<<dim3(HKP / 32, C_DIM / 32), dim3(32, 8), 0, stream>>>(
        Wq, Wqt, C_DIM, HK, HKP);
    transpose_cvt<<<dim3(OUT_DIM / 32, C_DIM / 32), dim3(32, 8), 0, stream>>>(
        W2, W2t, C_DIM, OUT_DIM, OUT_DIM);

    // 1) h = bf16(x @ W1 + b1)   [256 wgs, 512 thr, 1 block/CU]
    gemm8p<true><<<dim3(256), dim3(512), 0, stream>>>(xb, W1t, b1, hb, C_DIM);

    // 2) q = h @ Wq + bq   [16384 x 112]
    gemm_mfma<false, true>
        <<<dim3(1, M_DIM / 128), dim3(256), 0, stream>>>(
            hb, Wqt, bq, q, C_DIM, HK, HK);

    // 3+4) conv = bf16(dynconv(h, softmax(q)) + conv_bias)
    dynconv_bf16<<<dim3(M_DIM), dim3(256), 0, stream>>>(hb, q, cbias, convb);

    // 5) out = conv @ W2 + b2
    gemm8p<false><<<dim3(256), dim3(512), 0, stream>>>(convb, W2t, b2, out,
                                                       OUT_DIM);
}